// Round 14
// baseline (27.463 us; speedup 1.0000x reference)
//
#include <hip/hip_runtime.h>
#include <math.h>

// ---------------------------------------------------------------------------
// RISVQCLayer: angles = tanh(fused @ W^T + b) * pi  -> 4-qubit VQC -> (z+1)*pi
// B=65536, HID=256, R=16 runs (64 outputs/sample), fp32 in/out.
//
// R13 = R12 + residency push (the one axis not yet cleanly tested):
//  - ua prefetch DEFERRED to Phase B (consumed last, L2-hot, TLP-hidden)
//    -> -16 VGPR in the high-pressure region. af stays hoisted (R11 showed
//    de-hoisting af costs ~2us: it is GEMM-critical).
//  - __launch_bounds__(256,5): VGPR cap ~102 -> 5 blocks/CU resident
//    (was 4), work 8/CU -> 1.6 rounds instead of 2.0.
//  - tab aliases tile LDS (16.4 KB), prologue order HBM-first (R12).
// GEMM (16x16x32, XOR-swizzled LDS B-frags), Phase A (tanh->sincos->factor
// tab, wave-private), Phase B (one mfma_32x32x16 per run, [U_hi;U_lo] split
// fp16 = exact U, hi/lo combine in-lane, single shfl_xor(32)) all verified.
// d_ws: [0,32K) Wf fp16 frags; [32K,48K) UA32 fp16 frags; [48K,64K) U fp32.
// ---------------------------------------------------------------------------

#define PI_F 3.14159265358979323846f

typedef _Float16 f16x4 __attribute__((ext_vector_type(4)));
typedef _Float16 f16x8 __attribute__((ext_vector_type(8)));
typedef float    f32x4 __attribute__((ext_vector_type(4)));
typedef float    f32x16 __attribute__((ext_vector_type(16)));

__device__ __forceinline__ void ry_gate(float st[16], float c, float s, int w) {
    const int m = 1 << (3 - w);
    #pragma unroll
    for (int i = 0; i < 16; ++i) {
        if (i & m) continue;
        float a = st[i];
        float b = st[i | m];
        st[i]     = c * a - s * b;
        st[i | m] = s * a + c * b;
    }
}

__device__ __forceinline__ void cnot_gate(float st[16], int cw, int tw) {
    const int cm = 1 << (3 - cw);
    const int tm = 1 << (3 - tw);
    #pragma unroll
    for (int i = 0; i < 16; ++i) {
        if ((i & cm) && !(i & tm)) {
            float tmp = st[i];
            st[i] = st[i | tm];
            st[i | tm] = tmp;
        }
    }
}

// prep: block0 -> U matrices then UA32 fragments; block1 -> W frags.
// (layouts verified R3-R12)
__global__ void prep_kernel(const float* __restrict__ vw,
                            const float* __restrict__ W,
                            char* __restrict__ ws) {
    const int tid = threadIdx.x;   // 256
    if (blockIdx.x == 0) {
        float* Ut = (float*)(ws + 49152);          // fp32 U[r][i][j]
        {   // phase 1: thread (r, j) computes column j of U_r
            const int r = tid >> 4, j = tid & 15;
            const float* wr = vw + r * 16;
            float cs[16], sn[16];
            #pragma unroll
            for (int i = 0; i < 16; ++i) {
                float h = wr[i] * 0.5f;
                cs[i] = __cosf(h);
                sn[i] = __sinf(h);
            }
            float st[16];
            #pragma unroll
            for (int i = 0; i < 16; ++i) st[i] = 0.f;
            st[j] = 1.f;
            #pragma unroll
            for (int w = 0; w < 4; ++w) ry_gate(st, cs[w], sn[w], w);
            cnot_gate(st, 0, 1);
            cnot_gate(st, 2, 3);
            #pragma unroll
            for (int w = 0; w < 4; ++w) ry_gate(st, cs[4 + w], sn[4 + w], w);
            cnot_gate(st, 1, 2);
            cnot_gate(st, 3, 0);
            #pragma unroll
            for (int w = 0; w < 4; ++w) ry_gate(st, cs[8 + w], sn[8 + w], w);
            cnot_gate(st, 0, 1);
            cnot_gate(st, 1, 2);
            cnot_gate(st, 2, 3);
            cnot_gate(st, 3, 0);
            #pragma unroll
            for (int w = 0; w < 4; ++w) ry_gate(st, cs[12 + w], sn[12 + w], w);
            #pragma unroll
            for (int i = 0; i < 16; ++i) Ut[r * 256 + i * 16 + j] = st[i];
        }
        __syncthreads();
        {   // phase 2: UA32[r][lane]: i=lane&31, h=lane>>5, k=8h+e (K=16):
            //          i<16 -> hi(U[i][k]); i>=16 -> lo(U[i-16][k])
            _Float16* UA = (_Float16*)(ws + 32768);
            #pragma unroll
            for (int t = 0; t < 4; ++t) {
                int f = t * 256 + tid;             // 0..1023
                int r = f >> 6, lane = f & 63;
                int i = lane & 31, hh = lane >> 5;
                const float* urow = Ut + r * 256 + (i & 15) * 16;
                f16x8 h;
                #pragma unroll
                for (int e = 0; e < 8; ++e) {
                    float u = urow[8 * hh + e];
                    if (i < 16) {
                        h[e] = (_Float16)u;
                    } else {
                        _Float16 hi = (_Float16)u;
                        h[e] = (_Float16)(u - (float)hi);
                    }
                }
                *(f16x8*)(UA + f * 8) = h;
            }
        }
    } else {
        // W fragments: row=cg*16+l15, k=(kk*4+l4)*8+e
        _Float16* Wh = (_Float16*)ws;
        #pragma unroll
        for (int t = 0; t < 8; ++t) {
            int f  = tid * 8 + t;            // fragment id 0..2047
            int cg = f >> 9;
            int kk = (f >> 6) & 7;
            int l  = f & 63;
            int row = cg * 16 + (l & 15);
            int k0  = (kk * 4 + (l >> 4)) * 8;
            const float* src = W + row * 256 + k0;
            f16x8 h;
            #pragma unroll
            for (int e = 0; e < 8; ++e) h[e] = (_Float16)src[e];
            *(f16x8*)(Wh + f * 8) = h;
        }
    }
}

__global__ __launch_bounds__(256, 5) void vqc_main_kernel(
        const float* __restrict__ fused,   // (65536, 256)
        const char* __restrict__ ws,       // Wf + UA32 fragments
        const float* __restrict__ bp,      // (64,)
        float* __restrict__ out) {         // (65536, 64)
    // [0,16384): fused tile fp16 swizzled (32 rows x 512B) during GEMM;
    //            after barrier #2 the first 8KB is reused as tab.
    __shared__ __align__(16) char smem[16384];
    _Float16* tab = (_Float16*)smem;       // [16 runs][32 samples] x8 fp16

    const int tid  = threadIdx.x;
    const int lane = tid & 63;
    const int cg   = tid >> 6;             // wave id = run group
    const int l15  = lane & 15;
    const int l4   = lane >> 4;
    const size_t b0 = (size_t)blockIdx.x * 32;

    // ---- 1. issue fused tile loads FIRST (HBM, longest latency) ----
    float4 stg[8];
    {
        const float4* s4 = (const float4*)(fused + b0 * 256);
        #pragma unroll
        for (int it = 0; it < 8; ++it) stg[it] = s4[tid + it * 256];
    }

    // ---- 2. hoisted L2 prefetches: af / bias (ua deferred to Phase B) ----
    const f16x8* Wf = (const f16x8*)ws;
    f16x8 af[8];
    #pragma unroll
    for (int kk = 0; kk < 8; ++kk) af[kk] = Wf[(cg * 8 + kk) * 64 + lane];

    float4 bb = *(const float4*)(bp + 4 * (4 * cg + l4));   // lane's run bias

    // ---- 3. stage convert stg -> tile fp16, XOR-swizzled ----
    #pragma unroll
    for (int it = 0; it < 8; ++it) {
        int q = tid + it * 256;            // float4 index within tile
        float4 v = stg[it];
        int row = q >> 6;
        int c4  = (q & 63) << 2;
        int sl  = (c4 >> 3) ^ (row & 7);
        int byteoff = row * 512 + (sl << 4) + ((c4 & 7) << 1);
        f16x4 h = { (_Float16)v.x, (_Float16)v.y, (_Float16)v.z, (_Float16)v.w };
        *(f16x4*)(smem + byteoff) = h;
    }
    __syncthreads();                       // barrier #1: tile ready

    // ---- 4. GEMM: acc[sg][j] = pre[sample sg*16+l15][angle 16cg+4l4+j] ----
    f32x4 acc[2] = {};
    #pragma unroll
    for (int kk = 0; kk < 8; ++kk) {
        int slot = kk * 4 + l4;
        #pragma unroll
        for (int sg = 0; sg < 2; ++sg) {
            int frow = sg * 16 + l15;
            f16x8 bf = *(const f16x8*)(smem + frow * 512 + ((slot ^ (frow & 7)) << 4));
            acc[sg] = __builtin_amdgcn_mfma_f32_16x16x32_f16(af[kk], bf, acc[sg], 0, 0, 0);
        }
    }
    __syncthreads();                       // barrier #2: tile dead; tab aliases

    // ---- 5. Phase A: lane owns run r_own; factor table (wave-private) ----
    const int r_own = 4 * cg + l4;
    #pragma unroll
    for (int sg = 0; sg < 2; ++sg) {
        float bias[4] = {bb.x, bb.y, bb.z, bb.w};
        float cc[4], ssn[4];
        #pragma unroll
        for (int w = 0; w < 4; ++w) {
            float pre = acc[sg][w] + bias[w];
            float e   = __expf(2.f * pre);
            float th  = __fdividef(e - 1.f, e + 1.f);   // tanh(pre)
            float ha  = th * (0.5f * PI_F);             // theta/2
            __sincosf(ha, &ssn[w], &cc[w]);
        }
        f16x8 tt;
        tt[0] = (_Float16)(cc[0] * cc[1]);  tt[1] = (_Float16)(cc[0] * ssn[1]);
        tt[2] = (_Float16)(ssn[0] * cc[1]); tt[3] = (_Float16)(ssn[0] * ssn[1]);
        tt[4] = (_Float16)(cc[2] * cc[3]);  tt[5] = (_Float16)(cc[2] * ssn[3]);
        tt[6] = (_Float16)(ssn[2] * cc[3]); tt[7] = (_Float16)(ssn[2] * ssn[3]);
        *(f16x8*)(tab + (r_own * 32 + sg * 16 + l15) * 8) = tt;
    }
    // tab region [4cg..4cg+3] written & read by wave cg only -> no barrier.

    // ---- 6. Phase B: per run ONE mfma_32x32x16 over all 32 samples ----
    const f16x8* UA = (const f16x8*)(ws + 32768);
    const int   s32 = lane & 31;           // sample within tile
    const int   hh  = lane >> 5;           // state half (bit2 of state)
    const float g1  = hh ? -1.f : 1.f;

    #pragma unroll
    for (int rr = 0; rr < 4; ++rr) {
        const int r = 4 * cg + rr;
        f16x8 ua = UA[r * 64 + lane];      // deferred load: L2-hot, TLP-hidden
        f16x8 tt = *(const f16x8*)(tab + (r * 32 + s32) * 8);
        _Float16 a0 = tt[2 * hh], a1 = tt[2 * hh + 1];
        f16x8 se;
        se[0] = a0 * tt[4]; se[1] = a0 * tt[5];
        se[2] = a0 * tt[6]; se[3] = a0 * tt[7];
        se[4] = a1 * tt[4]; se[5] = a1 * tt[5];
        se[6] = a1 * tt[6]; se[7] = a1 * tt[7];

        f32x16 zero = {};
        f32x16 o = __builtin_amdgcn_mfma_f32_32x32x16_f16(ua, se, zero, 0, 0, 0);

        // combine hi/lo: full state s' = (j&3)+8*(j>>2)+4*hh, j=0..7
        float p[8];
        #pragma unroll
        for (int j = 0; j < 8; ++j) {
            float of = o[j] + o[j + 8];
            p[j] = of * of;
        }
        float a = p[0] + p[1], b = p[2] + p[3];
        float c = p[4] + p[5], d = p[6] + p[7];
        float ab = a + b, cd = c + d;
        float z0 = ab - cd;                 // bit3 sign
        float z1 = g1 * (ab + cd);          // bit2 = hh
        float z2 = (a - b) + (c - d);       // bit1
        float z3 = (p[0] - p[1] + p[2] - p[3]) + (p[4] - p[5] + p[6] - p[7]);

        z0 += __shfl_xor(z0, 32);
        z1 += __shfl_xor(z1, 32);
        z2 += __shfl_xor(z2, 32);
        z3 += __shfl_xor(z3, 32);

        if (hh == 0) {
            float4 ov;
            ov.x = (z0 + 1.f) * PI_F;
            ov.y = (z1 + 1.f) * PI_F;
            ov.z = (z2 + 1.f) * PI_F;
            ov.w = (z3 + 1.f) * PI_F;
            *(float4*)(out + (b0 + s32) * 64 + 4 * r) = ov;
        }
    }
}

extern "C" void kernel_launch(void* const* d_in, const int* in_sizes, int n_in,
                              void* d_out, int out_size, void* d_ws, size_t ws_size,
                              hipStream_t stream) {
    const float* fused = (const float*)d_in[0];   // (65536, 256)
    const float* Wp    = (const float*)d_in[1];   // (64, 256)
    const float* bp    = (const float*)d_in[2];   // (64,)
    const float* vw    = (const float*)d_in[3];   // (16, 4, 4)
    float* out = (float*)d_out;                   // (65536, 64)
    char*  ws  = (char*)d_ws;                     // 64 KB used

    prep_kernel<<<2, 256, 0, stream>>>(vw, Wp, ws);

    const int B = 65536;
    vqc_main_kernel<<<B / 32, 256, 0, stream>>>(fused, ws, bp, out);
}